// Round 1
// baseline (743.894 us; speedup 1.0000x reference)
//
#include <hip/hip_runtime.h>

typedef unsigned int uint;
typedef unsigned short ushort;
typedef unsigned long long u64;

typedef __attribute__((ext_vector_type(8))) short short8;
typedef __attribute__((ext_vector_type(4))) float floatx4;

// ---------------- helpers ----------------
__device__ inline ushort bf16rne(float v) {
  uint b = __float_as_uint(v);
  uint r = (b + 0x7fffu + ((b >> 16) & 1u)) >> 16;
  return (ushort)r;
}

__device__ inline void gl_lds16(const void* g, void* l) {
  __builtin_amdgcn_global_load_lds(
      (const __attribute__((address_space(1))) unsigned int*)g,
      (__attribute__((address_space(3))) unsigned int*)l, 16, 0, 0);
}

// ---------------- prep: x -> padded transposed bf16 hi/lo [66][66][1024] ----
__global__ __launch_bounds__(256) void prep_x(const float* __restrict__ x,
                                              ushort* __restrict__ xh,
                                              ushort* __restrict__ xl) {
  __shared__ float tile[64 * 65];
  int ci0 = blockIdx.x * 64, y = blockIdx.y, t = threadIdx.x;
#pragma unroll
  for (int it = 0; it < 16; ++it) {
    int L = t + 256 * it;
    int cl = L >> 6, xx = L & 63;
    tile[cl * 65 + xx] = x[(size_t)(ci0 + cl) * 4096 + y * 64 + xx];
  }
  __syncthreads();
#pragma unroll
  for (int it = 0; it < 16; ++it) {
    int L = t + 256 * it;
    int xx = L >> 6, cl = L & 63;
    float v = tile[cl * 65 + xx];
    ushort h2 = bf16rne(v);
    float hf = __uint_as_float((uint)h2 << 16);
    ushort l2 = bf16rne(v - hf);
    size_t oi = ((size_t)((y + 1) * 66 + (xx + 1))) * 1024 + ci0 + cl;
    xh[oi] = h2;
    xl[oi] = l2;
  }
}

// ---------------- prep: conv_w[co][ci][3][3] -> wT[off][co][ci] hi/lo -------
__global__ __launch_bounds__(256) void prep_w(const float* __restrict__ w,
                                              ushort* __restrict__ wh,
                                              ushort* __restrict__ wl) {
  __shared__ float tile[2304];  // 256 ci x 9 off
  int co = blockIdx.x, ci0 = blockIdx.y * 256, t = threadIdx.x;
  const float* src = w + ((size_t)co * 1024 + ci0) * 9;
  for (int i = t; i < 2304; i += 256) tile[i] = src[i];
  __syncthreads();
  int ci = ci0 + t;
#pragma unroll
  for (int off = 0; off < 9; ++off) {
    float v = tile[t * 9 + off];
    ushort h2 = bf16rne(v);
    float hf = __uint_as_float((uint)h2 << 16);
    ushort l2 = bf16rne(v - hf);
    size_t oi = ((size_t)off << 20) | ((size_t)co << 10) | (size_t)ci;
    wh[oi] = h2;
    wl[oi] = l2;
  }
}

// ---------------- prep: head weights [128][1024] hi/lo + bias[128] ----------
__global__ __launch_bounds__(256) void prep_head(
    const float* __restrict__ score_w, const float* __restrict__ loc_w,
    const float* __restrict__ score_b, const float* __restrict__ loc_b,
    ushort* __restrict__ wh, ushort* __restrict__ wl, float* __restrict__ bh) {
  int idx = blockIdx.x * 256 + threadIdx.x;  // < 131072
  int o = idx >> 10, ci = idx & 1023;
  float v = 0.f;
  if (o < 15) v = score_w[o * 1024 + ci];
  else if (o < 75) v = loc_w[(o - 15) * 1024 + ci];
  ushort h2 = bf16rne(v);
  float hf = __uint_as_float((uint)h2 << 16);
  wh[idx] = h2;
  wl[idx] = bf16rne(v - hf);
  if (idx < 128) bh[idx] = (idx < 15) ? score_b[idx] : ((idx < 75) ? loc_b[idx - 15] : 0.f);
}

// ---------------- bf16x3 GEMM: C[m][n] = sum_k A[m][k]*B[n][k] --------------
// IM2COL=1: A from xpadT (im2col, K=9216), epilogue bias+relu -> h hi/lo bf16
// IM2COL=0: A = h[m][k] (K=1024), epilogue bias -> raw f32 [m][128]
template <int IM2COL>
__global__ __launch_bounds__(256, 1) void gemm_bf16x3(
    const ushort* __restrict__ Ahi, const ushort* __restrict__ Alo,
    const ushort* __restrict__ Bhi, const ushort* __restrict__ Blo,
    const float* __restrict__ bias, int nChunks, float* __restrict__ outRaw,
    ushort* __restrict__ outHi, ushort* __restrict__ outLo) {
  __shared__ ushort sm[2 * 4 * 128 * 32];  // 64 KB: 2 bufs x {Ah,Al,Bh,Bl} x 128x32
  const int t = threadIdx.x;
  const int m0 = blockIdx.x * 128;
  const int n0 = blockIdx.y * 128;

  auto stage = [&](int kc, int bufIdx) {
    char* lds = (char*)sm + bufIdx * 32768;
    int off = 0, cc = 0, oy = 0, ox = 0;
    if (IM2COL) {
      off = kc >> 5;            // 0..8  (ky*3+kx)
      cc = (kc & 31) << 5;      // ci0
      oy = off / 3;
      ox = off - 3 * oy;
    }
#pragma unroll
    for (int q = 0; q < 2; ++q) {
      int L = t + 256 * q, row = L >> 2, seg = L & 3;
      size_t aoff, boff;
      if (IM2COL) {
        int m = m0 + row, y = m >> 6, xq = m & 63;
        aoff = ((size_t)((y + oy) * 66 + (xq + ox)) * 1024 + (size_t)cc) * 2 + seg * 16;
        boff = (((size_t)off << 20) + ((size_t)(n0 + row) << 10) + (size_t)cc) * 2 + seg * 16;
      } else {
        aoff = (((size_t)(m0 + row) << 10) + (size_t)kc * 32) * 2 + seg * 16;
        boff = (((size_t)(n0 + row) << 10) + (size_t)kc * 32) * 2 + seg * 16;
      }
      int dst = L * 16;
      gl_lds16((const char*)Ahi + aoff, lds + dst);
      gl_lds16((const char*)Alo + aoff, lds + 8192 + dst);
      gl_lds16((const char*)Bhi + boff, lds + 16384 + dst);
      gl_lds16((const char*)Blo + boff, lds + 24576 + dst);
    }
  };

  const int lane = t & 63, wv = t >> 6;
  const int wm = (wv & 1) * 64, wn = (wv >> 1) * 64;
  const int arow = wm + (lane & 15);
  const int brow = wn + (lane & 15);
  const int ko = (lane >> 4) * 8;

  floatx4 acc[4][4];
#pragma unroll
  for (int i = 0; i < 4; ++i)
#pragma unroll
    for (int j = 0; j < 4; ++j) acc[i][j] = (floatx4){0.f, 0.f, 0.f, 0.f};

  stage(0, 0);
  for (int kc = 0; kc < nChunks; ++kc) {
    __syncthreads();  // staged chunk kc landed; prev compute done
    if (kc + 1 < nChunks) stage(kc + 1, (kc + 1) & 1);  // overlap with compute below
    const ushort* sb = sm + (kc & 1) * 16384;
    const ushort* sAh = sb;
    const ushort* sAl = sb + 4096;
    const ushort* sBh = sb + 8192;
    const ushort* sBl = sb + 12288;
    short8 ah[4], al[4], bh2[4], bl2[4];
#pragma unroll
    for (int i = 0; i < 4; ++i) {
      ah[i] = *(const short8*)(sAh + (arow + 16 * i) * 32 + ko);
      al[i] = *(const short8*)(sAl + (arow + 16 * i) * 32 + ko);
      bh2[i] = *(const short8*)(sBh + (brow + 16 * i) * 32 + ko);
      bl2[i] = *(const short8*)(sBl + (brow + 16 * i) * 32 + ko);
    }
#pragma unroll
    for (int i = 0; i < 4; ++i)
#pragma unroll
      for (int j = 0; j < 4; ++j) {
        acc[i][j] = __builtin_amdgcn_mfma_f32_16x16x32_bf16(ah[i], bh2[j], acc[i][j], 0, 0, 0);
        acc[i][j] = __builtin_amdgcn_mfma_f32_16x16x32_bf16(ah[i], bl2[j], acc[i][j], 0, 0, 0);
        acc[i][j] = __builtin_amdgcn_mfma_f32_16x16x32_bf16(al[i], bh2[j], acc[i][j], 0, 0, 0);
      }
  }

#pragma unroll
  for (int i = 0; i < 4; ++i)
#pragma unroll
    for (int j = 0; j < 4; ++j) {
      int nn = n0 + wn + 16 * j + (lane & 15);
      float bv = bias[nn];
#pragma unroll
      for (int r = 0; r < 4; ++r) {
        int mm = m0 + wm + 16 * i + (lane >> 4) * 4 + r;  // C: row=(lane>>4)*4+reg
        float v = acc[i][j][r] + bv;
        if (IM2COL) {
          v = fmaxf(v, 0.f);
          ushort h2 = bf16rne(v);
          float hf = __uint_as_float((uint)h2 << 16);
          ushort l2 = bf16rne(v - hf);
          outHi[(size_t)mm * 1024 + nn] = h2;
          outLo[(size_t)mm * 1024 + nn] = l2;
        } else {
          outRaw[(size_t)mm * 128 + nn] = v;
        }
      }
    }
}

// ---------------- decode + key + histogram ----------------------------------
__global__ __launch_bounds__(256) void decode_k(const float* __restrict__ raw,
                                                float* __restrict__ scores,
                                                float4* __restrict__ boxes,
                                                uint* __restrict__ key32,
                                                uint* __restrict__ hist) {
  int i = blockIdx.x * 256 + threadIdx.x;  // exactly 61440
  int m = i / 15, a = i - m * 15;
  int y = m >> 6, x = m & 63;
  const float* rp = raw + (size_t)m * 128;
  float logit = rp[a];
  float dx = rp[15 + 4 * a], dy = rp[16 + 4 * a];
  float dw = rp[17 + 4 * a], dh = rp[18 + 4 * a];
  int rr = a / 5, ss = a - rr * 5;
  float sc5 = (float)(2 << ss);
  float W = ((rr == 0) ? 23.f : (rr == 1) ? 16.f : 11.f) * sc5;
  float H = ((rr == 0) ? 12.f : (rr == 1) ? 16.f : 22.f) * sc5;
  float aw = W - 1.f, ah = H - 1.f;
  float ax = x * 16.f + 7.5f, ay = y * 16.f + 7.5f;
  float ox = dx * aw + ax, oyc = dy * ah + ay;
  float ow = expf(fminf(dw, 4.14f)) * aw * 0.5f;
  float oh = expf(fminf(dh, 4.14f)) * ah * 0.5f;
  float x1 = fminf(fmaxf(ox - ow, 0.f), 1023.f);
  float y1 = fminf(fmaxf(oyc - oh, 0.f), 1023.f);
  float x2 = fminf(fmaxf(ox + ow, 0.f), 1023.f);
  float y2 = fminf(fmaxf(oyc + oh, 0.f), 1023.f);
  bool inval = ((x2 - x1) < 16.f) || ((y2 - y1) < 16.f);
  float sc = inval ? -1.f : (1.f / (1.f + expf(-logit)));
  scores[i] = sc;
  boxes[i] = inval ? make_float4(-1.f, -1.f, -1.f, -1.f) : make_float4(x1, y1, x2, y2);
  uint kb = __float_as_uint(sc);
  uint key = (kb & 0x80000000u) ? ~kb : (kb | 0x80000000u);
  key32[i] = key;
  atomicAdd(&hist[key >> 16], 1u);
}

// ---------------- find 16-bit prefix threshold for top-6000 -----------------
__global__ __launch_bounds__(256) void find_t16(const uint* __restrict__ hist,
                                                uint* __restrict__ selT) {
  __shared__ uint ps[256];
  __shared__ int segS;
  int t = threadIdx.x;
  uint s = 0;
  const uint* hp = hist + t * 256;
  for (int i = 0; i < 256; ++i) s += hp[i];
  ps[t] = s;
  __syncthreads();
  for (int d = 1; d < 256; d <<= 1) {
    uint v = ps[t] + ((t + d < 256) ? ps[t + d] : 0u);
    __syncthreads();
    ps[t] = v;
    __syncthreads();
  }
  if (ps[t] >= 6000u && (t == 255 || ps[t + 1] < 6000u)) segS = t;
  __syncthreads();
  int sg = segS;
  uint base = (sg == 255) ? 0u : ps[sg + 1];
  uint h2 = hist[sg * 256 + t];
  __syncthreads();
  ps[t] = h2;
  __syncthreads();
  for (int d = 1; d < 256; d <<= 1) {
    uint v = ps[t] + ((t + d < 256) ? ps[t + d] : 0u);
    __syncthreads();
    ps[t] = v;
    __syncthreads();
  }
  if (base + ps[t] >= 6000u && (t == 255 || base + ps[t + 1] < 6000u))
    *selT = (uint)(sg * 256 + t);
}

// ---------------- gather candidates (prefix >= T16) -------------------------
__global__ __launch_bounds__(256) void gather_k(const uint* __restrict__ key32,
                                                const uint* __restrict__ selT,
                                                uint* __restrict__ cnt,
                                                u64* __restrict__ cand) {
  int i = blockIdx.x * 256 + threadIdx.x;  // exactly 61440
  uint T = *selT;
  uint k = key32[i];
  if ((k >> 16) >= T) {
    uint pos = atomicAdd(cnt, 1u);
    if (pos < 8192) cand[pos] = ((u64)k << 32) | (u64)(~(uint)i);
  }
}

// ---------------- single-block bitonic sort (desc) + gather top-6000 --------
__global__ __launch_bounds__(1024) void sort_gather(
    const u64* __restrict__ cand, const uint* __restrict__ cnt,
    const float* __restrict__ scores, const float4* __restrict__ boxes,
    float* __restrict__ sortedS, float4* __restrict__ sortedB) {
  extern __shared__ u64 sk[];  // 8192 * 8 = 64 KB
  int t = threadIdx.x;
  int C = (int)*cnt;
  if (C > 8192) C = 8192;
  for (int j = t; j < 8192; j += 1024) sk[j] = (j < C) ? cand[j] : 0ull;
  __syncthreads();
  for (int k = 2; k <= 8192; k <<= 1) {
    for (int j2 = k >> 1; j2 > 0; j2 >>= 1) {
      for (int p = t; p < 4096; p += 1024) {
        int i = ((p & ~(j2 - 1)) << 1) | (p & (j2 - 1));
        int ix = i | j2;
        u64 a = sk[i], b = sk[ix];
        bool ddir = (i & k) != 0;
        if ((a < b) != ddir) { sk[i] = b; sk[ix] = a; }
      }
      __syncthreads();
    }
  }
  for (int j = t; j < 6016; j += 1024) {
    if (j < 6000) {
      u64 key = sk[j];
      uint idx = ~(uint)(key & 0xffffffffu);
      sortedS[j] = scores[idx];
      sortedB[j] = boxes[idx];
    } else {
      sortedS[j] = -1.f;
      sortedB[j] = make_float4(0.f, 0.f, 0.f, 0.f);
    }
  }
}

// ---------------- IoU suppression bitmask: mask[row][128 u64 words] ---------
__global__ __launch_bounds__(64) void iou_mask(const float4* __restrict__ boxes,
                                               u64* __restrict__ mask) {
  __shared__ float cx1[64], cy1[64], cx2[64], cy2[64], car[64];
  int bi = blockIdx.x, bj = blockIdx.y, t = threadIdx.x;
  float4 cb = boxes[bj * 64 + t];
  cx1[t] = cb.x; cy1[t] = cb.y; cx2[t] = cb.z; cy2[t] = cb.w;
  car[t] = (cb.z - cb.x) * (cb.w - cb.y);
  __syncthreads();
  int r = bi * 64 + t;
  float4 rb = boxes[r];
  float ra = (rb.z - rb.x) * (rb.w - rb.y);
  u64 wd = 0;
#pragma unroll 8
  for (int j = 0; j < 64; ++j) {
    float iw = fmaxf(fminf(rb.z, cx2[j]) - fmaxf(rb.x, cx1[j]), 0.f);
    float ih = fmaxf(fminf(rb.w, cy2[j]) - fmaxf(rb.y, cy1[j]), 0.f);
    float inter = iw * ih;
    float iou = inter / (ra + car[j] - inter + 1e-12f);
    if (iou > 0.7f && r != bj * 64 + j) wd |= (1ull << j);
  }
  mask[(size_t)r * 128 + bj] = wd;
}

// ---------------- serial NMS scan (1 wave), word-skipping, early stop -------
__global__ __launch_bounds__(64) void nms_scan(const u64* __restrict__ mask,
                                               const float* __restrict__ sortedS,
                                               const float4* __restrict__ sortedB,
                                               float* __restrict__ out) {
  __shared__ int klist[300];
  int lane = threadIdx.x;
  u64 Sx = 0, Sy = 0;  // lane l owns suppression words 2l and 2l+1
  for (int w2 = 0; w2 < 94; ++w2) {
    bool neg = sortedS[w2 * 64 + lane] < 0.f;
    u64 m2 = __ballot(neg);
    if ((w2 >> 1) == lane) { if (w2 & 1) Sy = m2; else Sx = m2; }
  }
  int count = 0;
  for (int w2 = 0; w2 < 94; ++w2) {
    u64 cur = __shfl((w2 & 1) ? Sy : Sx, w2 >> 1);
    u64 rem = ~cur;
    if (w2 == 93) rem &= (1ull << 48) - 1;  // rows 6000..6015 are pad
    while (rem) {
      int b = __builtin_ctzll(rem);
      int i = w2 * 64 + b;
      if (lane == 0) klist[count] = i;
      count++;
      if (count == 300) goto done;
      const ulonglong2* rp = (const ulonglong2*)(mask + (size_t)i * 128);
      ulonglong2 rv = rp[lane];
      Sx |= rv.x;
      Sy |= rv.y;
      u64 cur2 = __shfl((w2 & 1) ? Sy : Sx, w2 >> 1);
      rem &= ~cur2;
      rem &= (b == 63) ? 0ull : (~0ull << (b + 1));
    }
  }
done:
  __syncthreads();
  for (int j = lane; j < 300; j += 64) {
    float s;
    float4 bb;
    if (j < count) {
      int i = klist[j];
      s = sortedS[i];
      bb = sortedB[i];
    } else {
      s = -1.f;
      bb = make_float4(-1.f, -1.f, -1.f, -1.f);
    }
    out[j * 5 + 0] = s;
    out[j * 5 + 1] = bb.x;
    out[j * 5 + 2] = bb.y;
    out[j * 5 + 3] = bb.z;
    out[j * 5 + 4] = bb.w;
  }
}

// ---------------- workspace layout (bytes) ----------------------------------
constexpr size_t O_XH = 0;                // 8,921,088   xpadT hi
constexpr size_t O_XL = 8921088;          // 8,921,088   xpadT lo
constexpr size_t O_WTH = 17842176;        // 18,874,368  wT hi
constexpr size_t O_WTL = 36716544;        // 18,874,368  wT lo
constexpr size_t O_HH = 55590912;         // 8,388,608   h hi
constexpr size_t O_HL = 63979520;         // 8,388,608   h lo
constexpr size_t O_WHH = 72368128;        // 262,144     head w hi
constexpr size_t O_WHL = 72630272;        // 262,144     head w lo
constexpr size_t O_BHD = 72892416;        // 512         head bias
constexpr size_t O_SC = 72892928;         // 245,760     scores
constexpr size_t O_BX = 73138688;         // 983,040     boxes (float4)
constexpr size_t O_KEY = 74121728;        // 245,760     key32
constexpr size_t O_HIST = 74367488;       // 262,144     histogram
constexpr size_t O_CNT = 74629632;        // 256         atomic counter
constexpr size_t O_CAND = 74629888;       // 65,536      candidates
constexpr size_t O_SELT = 74695424;       // 256         T16
constexpr size_t O_SS = 74695680;         // 24,064      sorted scores [6016]
constexpr size_t O_SB = 74719744;         // 96,256      sorted boxes  [6016]
// aliases (regions dead by the time these are written):
constexpr size_t O_RAW = 0;               // 2,097,152  raw head out (aliases xpadT, dead after conv GEMM)
constexpr size_t O_MASK = 17842176;       // 6,160,384  NMS mask (aliases wT, dead after conv GEMM)
// total distinct footprint ~74.8 MB

extern "C" void kernel_launch(void* const* d_in, const int* in_sizes, int n_in,
                              void* d_out, int out_size, void* d_ws,
                              size_t ws_size, hipStream_t stream) {
  (void)in_sizes; (void)n_in; (void)out_size; (void)ws_size;
  const float* x = (const float*)d_in[1];
  const float* conv_w = (const float*)d_in[2];
  const float* conv_b = (const float*)d_in[3];
  const float* score_w = (const float*)d_in[4];
  const float* score_b = (const float*)d_in[5];
  const float* loc_w = (const float*)d_in[6];
  const float* loc_b = (const float*)d_in[7];
  float* out = (float*)d_out;
  char* ws = (char*)d_ws;

  ushort* xh = (ushort*)(ws + O_XH);
  ushort* xl = (ushort*)(ws + O_XL);
  ushort* wTh = (ushort*)(ws + O_WTH);
  ushort* wTl = (ushort*)(ws + O_WTL);
  ushort* hh = (ushort*)(ws + O_HH);
  ushort* hl = (ushort*)(ws + O_HL);
  ushort* wHh = (ushort*)(ws + O_WHH);
  ushort* wHl = (ushort*)(ws + O_WHL);
  float* biasH = (float*)(ws + O_BHD);
  float* raw = (float*)(ws + O_RAW);
  float* scores = (float*)(ws + O_SC);
  float4* boxes = (float4*)(ws + O_BX);
  uint* key32 = (uint*)(ws + O_KEY);
  uint* hist = (uint*)(ws + O_HIST);
  uint* cnt = (uint*)(ws + O_CNT);
  u64* cand = (u64*)(ws + O_CAND);
  uint* selT = (uint*)(ws + O_SELT);
  float* sortedS = (float*)(ws + O_SS);
  float4* sortedB = (float4*)(ws + O_SB);
  u64* mask = (u64*)(ws + O_MASK);

  // zero the padded-input borders (whole buffer) and histogram+counter
  hipMemsetAsync(ws + O_XH, 0, 2 * 8921088, stream);
  hipMemsetAsync(ws + O_HIST, 0, 262144 + 256, stream);

  prep_x<<<dim3(16, 64), 256, 0, stream>>>(x, xh, xl);
  prep_w<<<dim3(1024, 4), 256, 0, stream>>>(conv_w, wTh, wTl);
  prep_head<<<512, 256, 0, stream>>>(score_w, loc_w, score_b, loc_b, wHh, wHl, biasH);

  // conv: M=4096, N=1024, K=9*1024 -> h (relu, bf16 hi/lo)
  gemm_bf16x3<1><<<dim3(32, 8), 256, 0, stream>>>(xh, xl, wTh, wTl, conv_b, 288,
                                                  nullptr, hh, hl);
  // heads: M=4096, N=128(pad), K=1024 -> raw f32
  gemm_bf16x3<0><<<dim3(32, 1), 256, 0, stream>>>(hh, hl, wHh, wHl, biasH, 32,
                                                  raw, nullptr, nullptr);

  decode_k<<<240, 256, 0, stream>>>(raw, scores, boxes, key32, hist);
  find_t16<<<1, 256, 0, stream>>>(hist, selT);
  gather_k<<<240, 256, 0, stream>>>(key32, selT, cnt, cand);
  sort_gather<<<1, 1024, 65536, stream>>>(cand, cnt, scores, boxes, sortedS, sortedB);
  iou_mask<<<dim3(94, 94), 64, 0, stream>>>(sortedB, mask);
  nms_scan<<<1, 64, 0, stream>>>(mask, sortedS, sortedB, out);
}